// Round 1
// baseline (634.126 us; speedup 1.0000x reference)
//
#include <hip/hip_runtime.h>
#include <math.h>

// Problem constants
#define T_DIM 16
#define B_DIM 128
#define N_DIM 2048
#define TB    (T_DIM * B_DIM)   // 2048 rows of the GEMM

// ---------------------------------------------------------------------------
// Workspace layout (bytes). Total ~34.6 MB.
//   h      : [TB][N] fp64 GEMM result            @ 0          (32 MB)
//   ssum   : [TB] fp64 spatial sums              @ 33554432   (16 KB)
//   tsum   : [B*N] fp64 temporal sums            @ 33570816   (2 MB)
//   psum   : [16][N] fp64 col partial sums       @ 35667968   (256 KB)
//   psum2  : [16][N] fp64 col partial sq-sums    @ 35930112   (256 KB)
//   scale  : [N] fp64 BN scale (istd*gamma)      @ 36192256   (16 KB)
//   shift  : [N] fp64 BN shift (beta-mu*scale)   @ 36208640   (16 KB)
// ---------------------------------------------------------------------------
#define WS_H      0
#define WS_SSUM   33554432
#define WS_TSUM   33570816
#define WS_PSUM   35667968
#define WS_PSUM2  35930112
#define WS_SCALE  36192256
#define WS_SHIFT  36208640

// ---- spatial sum over last dim: one block per (t,b) row -------------------
__global__ __launch_bounds__(256)
void spatial_sum_kernel(const float* __restrict__ x, double* __restrict__ ssum) {
    int row = blockIdx.x;           // 0..TB-1  (= t*B + b)
    int tid = threadIdx.x;
    const float* xr = x + (size_t)row * N_DIM;
    double s = 0.0;
    for (int i = tid; i < N_DIM; i += 256) s += (double)xr[i];
    // wave (64-lane) reduce
    for (int off = 32; off > 0; off >>= 1) s += __shfl_down(s, off, 64);
    __shared__ double wsum[4];
    int lane = tid & 63, wv = tid >> 6;
    if (lane == 0) wsum[wv] = s;
    __syncthreads();
    if (tid == 0) ssum[row] = (wsum[0] + wsum[1]) + (wsum[2] + wsum[3]);
}

// ---- temporal sum over t: one thread per (b,n) ----------------------------
__global__ __launch_bounds__(256)
void temporal_sum_kernel(const float* __restrict__ x, double* __restrict__ tsum) {
    int idx = blockIdx.x * 256 + threadIdx.x;     // b*N + n
    double s = 0.0;
    for (int t = 0; t < T_DIM; ++t)
        s += (double)x[(size_t)t * (B_DIM * N_DIM) + idx];
    tsum[idx] = s;
}

// ---- GEMM h[row,m] = sum_n x[row,n] * W[m,n], fp64 accumulate -------------
// Both operands K-contiguous ("NT" shape): coalesced float4 loads.
// 64x64 block tile, BK=16, 256 threads, 4x4 fp64 acc/thread.
#define BK 16
__global__ __launch_bounds__(256)
void gemm_f64(const float* __restrict__ A, const float* __restrict__ Bw,
              double* __restrict__ C) {
    __shared__ double As[BK][65];   // +1 pad breaks store-phase bank aliasing
    __shared__ double Bs[BK][65];
    int tid = threadIdx.x;
    int tx = tid & 15;              // col group 0..15 (cols tx + 16*j)
    int ty = tid >> 4;              // row group 0..15 (rows ty + 16*i)
    int row0 = blockIdx.y * 64;
    int col0 = blockIdx.x * 64;
    int lr = tid >> 2;              // 0..63 : tile row loaded by this thread
    int lk = (tid & 3) * 4;         // 0,4,8,12 : k offset (float4)
    const float* Aptr = A + (size_t)(row0 + lr) * N_DIM + lk;
    const float* Bptr = Bw + (size_t)(col0 + lr) * N_DIM + lk;

    double acc[4][4];
#pragma unroll
    for (int i = 0; i < 4; ++i)
#pragma unroll
        for (int j = 0; j < 4; ++j) acc[i][j] = 0.0;

    for (int k0 = 0; k0 < N_DIM; k0 += BK) {
        float4 a4 = *(const float4*)(Aptr + k0);
        float4 b4 = *(const float4*)(Bptr + k0);
        __syncthreads();
        As[lk + 0][lr] = (double)a4.x; As[lk + 1][lr] = (double)a4.y;
        As[lk + 2][lr] = (double)a4.z; As[lk + 3][lr] = (double)a4.w;
        Bs[lk + 0][lr] = (double)b4.x; Bs[lk + 1][lr] = (double)b4.y;
        Bs[lk + 2][lr] = (double)b4.z; Bs[lk + 3][lr] = (double)b4.w;
        __syncthreads();
#pragma unroll
        for (int k = 0; k < BK; ++k) {
            double av[4], bv[4];
#pragma unroll
            for (int i = 0; i < 4; ++i) av[i] = As[k][ty + 16 * i];
#pragma unroll
            for (int j = 0; j < 4; ++j) bv[j] = Bs[k][tx + 16 * j];
#pragma unroll
            for (int i = 0; i < 4; ++i)
#pragma unroll
                for (int j = 0; j < 4; ++j)
                    acc[i][j] = fma(av[i], bv[j], acc[i][j]);
        }
    }
#pragma unroll
    for (int i = 0; i < 4; ++i) {
        int r = row0 + ty + 16 * i;
#pragma unroll
        for (int j = 0; j < 4; ++j)
            C[(size_t)r * N_DIM + col0 + tx + 16 * j] = acc[i][j];
    }
}

// ---- BN column stats, two-stage deterministic -----------------------------
__global__ __launch_bounds__(256)
void col_stats_partial(const double* __restrict__ h, double* __restrict__ psum,
                       double* __restrict__ psum2) {
    int m = blockIdx.x * 256 + threadIdx.x;       // 8 col blocks
    int chunk = blockIdx.y;                        // 16 row chunks of 128
    double s = 0.0, s2 = 0.0;
    int r0 = chunk * 128;
    for (int r = r0; r < r0 + 128; ++r) {
        double v = h[(size_t)r * N_DIM + m];
        s += v;
        s2 = fma(v, v, s2);
    }
    psum[chunk * N_DIM + m] = s;
    psum2[chunk * N_DIM + m] = s2;
}

__global__ __launch_bounds__(256)
void col_stats_final(const double* __restrict__ psum, const double* __restrict__ psum2,
                     const float* __restrict__ gamma, const float* __restrict__ beta,
                     double* __restrict__ scale, double* __restrict__ shift) {
    int m = blockIdx.x * 256 + threadIdx.x;
    double s = 0.0, s2 = 0.0;
    for (int c = 0; c < 16; ++c) { s += psum[c * N_DIM + m]; s2 += psum2[c * N_DIM + m]; }
    double mean = s * (1.0 / 2048.0);
    double var = s2 * (1.0 / 2048.0) - mean * mean;
    double istd = 1.0 / sqrt(var + 1e-5);
    double sc = istd * (double)gamma[m];
    scale[m] = sc;
    shift[m] = (double)beta[m] - mean * sc;
}

// ---- fused BN-apply + triple LIF + output ---------------------------------
// One thread per (b,n); sequential loop over t (LIF recurrence).
__global__ __launch_bounds__(256)
void fused_lif_kernel(const float* __restrict__ x, const double* __restrict__ h,
                      const double* __restrict__ scale, const double* __restrict__ shift,
                      const double* __restrict__ ssum, const double* __restrict__ tsum,
                      float* __restrict__ out) {
    int idx = blockIdx.x * 256 + threadIdx.x;     // b*N + n
    int n = idx & (N_DIM - 1);
    int b = idx >> 11;
    double sc = scale[n], sh = shift[n];
    double ts = tsum[idx];
    double v1 = 0.0, v2 = 0.0, v3 = 0.0;
    for (int t = 0; t < T_DIM; ++t) {
        size_t off = (size_t)(t * B_DIM + b) * N_DIM + n;
        double hv = fma(h[off], sc, sh);           // BN-applied value
        // LIF1: v = v/2 + hv (v - (v-0)/2 == v/2 exactly in binary fp)
        v1 = v1 * 0.5 + hv;
        bool s1 = (v1 >= 1.0); if (s1) v1 = 0.0;
        // LIF2 (spatial): input = s1 * spatial_sum[t,b]
        double in2 = s1 ? ssum[t * B_DIM + b] : 0.0;
        v2 = v2 * 0.5 + in2;
        bool s2 = (v2 >= 1.0); if (s2) v2 = 0.0;
        // LIF3 (temporal): input = s1 * temporal_sum[b,n]
        double in3 = s1 ? ts : 0.0;
        v3 = v3 * 0.5 + in3;
        bool s3 = (v3 >= 1.0); if (s3) v3 = 0.0;
        out[off] = x[off] + ((s2 && s3) ? 1.0f : 0.0f);
    }
}

extern "C" void kernel_launch(void* const* d_in, const int* in_sizes, int n_in,
                              void* d_out, int out_size, void* d_ws, size_t ws_size,
                              hipStream_t stream) {
    const float* x     = (const float*)d_in[0];   // [16,128,2048]
    const float* W     = (const float*)d_in[1];   // [2048,2048]
    const float* gamma = (const float*)d_in[2];   // [2048]
    const float* beta  = (const float*)d_in[3];   // [2048]
    float* out = (float*)d_out;

    char* ws = (char*)d_ws;                       // needs ~34.6 MB
    double* h     = (double*)(ws + WS_H);
    double* ssum  = (double*)(ws + WS_SSUM);
    double* tsum  = (double*)(ws + WS_TSUM);
    double* psum  = (double*)(ws + WS_PSUM);
    double* psum2 = (double*)(ws + WS_PSUM2);
    double* scale = (double*)(ws + WS_SCALE);
    double* shift = (double*)(ws + WS_SHIFT);

    spatial_sum_kernel<<<TB, 256, 0, stream>>>(x, ssum);
    temporal_sum_kernel<<<(B_DIM * N_DIM) / 256, 256, 0, stream>>>(x, tsum);
    gemm_f64<<<dim3(N_DIM / 64, TB / 64), 256, 0, stream>>>(x, W, h);
    col_stats_partial<<<dim3(8, 16), 256, 0, stream>>>(h, psum, psum2);
    col_stats_final<<<8, 256, 0, stream>>>(psum, psum2, gamma, beta, scale, shift);
    fused_lif_kernel<<<(B_DIM * N_DIM) / 256, 256, 0, stream>>>(x, h, scale, shift, ssum, tsum, out);
}

// Round 3
// 476.753 us; speedup vs baseline: 1.3301x; 1.3301x over previous
//
#include <hip/hip_runtime.h>
#include <math.h>

// Problem constants
#define T_DIM 16
#define B_DIM 128
#define N_DIM 2048
#define TB    (T_DIM * B_DIM)   // 2048 rows of the GEMM

// Workspace layout (bytes). Total ~36.3 MB.
#define WS_H      0
#define WS_SSUM   33554432
#define WS_TSUM   33570816
#define WS_PSUM   35667968
#define WS_PSUM2  35930112
#define WS_SCALE  36192256
#define WS_SHIFT  36208640

typedef __attribute__((ext_vector_type(2))) double d2;

// ---- spatial sum over last dim: one block per (t,b) row -------------------
__global__ __launch_bounds__(256)
void spatial_sum_kernel(const float* __restrict__ x, double* __restrict__ ssum) {
    int row = blockIdx.x;           // 0..TB-1  (= t*B + b)
    int tid = threadIdx.x;
    const float* xr = x + (size_t)row * N_DIM;
    double s = 0.0;
    for (int i = tid; i < N_DIM; i += 256) s += (double)xr[i];
    for (int off = 32; off > 0; off >>= 1) s += __shfl_down(s, off, 64);
    __shared__ double wsum[4];
    int lane = tid & 63, wv = tid >> 6;
    if (lane == 0) wsum[wv] = s;
    __syncthreads();
    if (tid == 0) ssum[row] = (wsum[0] + wsum[1]) + (wsum[2] + wsum[3]);
}

// ---- temporal sum over t: one thread per (b,n) ----------------------------
__global__ __launch_bounds__(256)
void temporal_sum_kernel(const float* __restrict__ x, double* __restrict__ tsum) {
    int idx = blockIdx.x * 256 + threadIdx.x;     // b*N + n
    double s = 0.0;
    for (int t = 0; t < T_DIM; ++t)
        s += (double)x[(size_t)t * (B_DIM * N_DIM) + idx];
    tsum[idx] = s;
}

// ---- GEMM h[row,m] = sum_n x[row,n] * W[m,n], fp64 vector FMA -------------
// 64x64 tile, ONE wave per block (64 threads), 8x8 doubles/thread.
// LDS layout [k][row] (stride 66 doubles): fragment reads are paired
// ds_read_b128, bank-group 4k+4{ty,tx} -> conflict-free with 8-lane
// broadcast. Accumulation order per output element identical to the R1
// kernel (k ascending, fp64 fma) -> bit-identical h.
#define BK 16
#define LDSS 66
__global__ __launch_bounds__(64, 1)
void gemm_f64_v2(const float* __restrict__ A, const float* __restrict__ Bw,
                 double* __restrict__ C) {
    __shared__ __align__(16) double As[BK * LDSS];
    __shared__ __align__(16) double Bs[BK * LDSS];
    const int t  = threadIdx.x;     // 0..63
    const int tx = t & 7;           // col pair-group
    const int ty = t >> 3;          // row pair-group
    const int row0 = blockIdx.y * 64;
    const int col0 = blockIdx.x * 64;

    const float* Ag = A  + (size_t)(row0 + t) * N_DIM;  // thread stages row t
    const float* Bg = Bw + (size_t)(col0 + t) * N_DIM;

    double acc[8][8];
#pragma unroll
    for (int i = 0; i < 8; ++i)
#pragma unroll
        for (int j = 0; j < 8; ++j) acc[i][j] = 0.0;

    // prefetch tile 0
    float4 sa[4], sb[4];
#pragma unroll
    for (int j = 0; j < 4; ++j) {
        sa[j] = *(const float4*)(Ag + 4 * j);
        sb[j] = *(const float4*)(Bg + 4 * j);
    }

    for (int k0 = 0; k0 < N_DIM; k0 += BK) {
        __syncthreads();
#pragma unroll
        for (int j = 0; j < 4; ++j) {
            As[(4 * j + 0) * LDSS + t] = (double)sa[j].x;
            As[(4 * j + 1) * LDSS + t] = (double)sa[j].y;
            As[(4 * j + 2) * LDSS + t] = (double)sa[j].z;
            As[(4 * j + 3) * LDSS + t] = (double)sa[j].w;
            Bs[(4 * j + 0) * LDSS + t] = (double)sb[j].x;
            Bs[(4 * j + 1) * LDSS + t] = (double)sb[j].y;
            Bs[(4 * j + 2) * LDSS + t] = (double)sb[j].z;
            Bs[(4 * j + 3) * LDSS + t] = (double)sb[j].w;
        }
        __syncthreads();
        if (k0 + BK < N_DIM) {          // prefetch next tile (overlaps compute)
#pragma unroll
            for (int j = 0; j < 4; ++j) {
                sa[j] = *(const float4*)(Ag + k0 + BK + 4 * j);
                sb[j] = *(const float4*)(Bg + k0 + BK + 4 * j);
            }
        }
#pragma unroll
        for (int k = 0; k < BK; ++k) {
            d2 av[4], bv[4];
#pragma unroll
            for (int i = 0; i < 4; ++i)
                av[i] = *(const d2*)&As[k * LDSS + 2 * ty + 16 * i];
#pragma unroll
            for (int j = 0; j < 4; ++j)
                bv[j] = *(const d2*)&Bs[k * LDSS + 2 * tx + 16 * j];
#pragma unroll
            for (int i = 0; i < 4; ++i)
#pragma unroll
                for (int j = 0; j < 4; ++j) {
                    acc[2*i  ][2*j  ] = fma(av[i].x, bv[j].x, acc[2*i  ][2*j  ]);
                    acc[2*i  ][2*j+1] = fma(av[i].x, bv[j].y, acc[2*i  ][2*j+1]);
                    acc[2*i+1][2*j  ] = fma(av[i].y, bv[j].x, acc[2*i+1][2*j  ]);
                    acc[2*i+1][2*j+1] = fma(av[i].y, bv[j].y, acc[2*i+1][2*j+1]);
                }
        }
    }

    // write-out: rows 2ty+16ip+e, col pairs 2tx+16jp
#pragma unroll
    for (int ip = 0; ip < 4; ++ip)
#pragma unroll
        for (int e = 0; e < 2; ++e) {
            int r = row0 + 2 * ty + 16 * ip + e;
            double* Crow = C + (size_t)r * N_DIM + col0 + 2 * tx;
#pragma unroll
            for (int jp = 0; jp < 4; ++jp) {
                d2 v;
                v.x = acc[2 * ip + e][2 * jp];
                v.y = acc[2 * ip + e][2 * jp + 1];
                *(d2*)(Crow + 16 * jp) = v;
            }
        }
}

// ---- BN column stats, two-stage deterministic -----------------------------
__global__ __launch_bounds__(256)
void col_stats_partial(const double* __restrict__ h, double* __restrict__ psum,
                       double* __restrict__ psum2) {
    int m = blockIdx.x * 256 + threadIdx.x;       // 8 col blocks
    int chunk = blockIdx.y;                        // 16 row chunks of 128
    double s = 0.0, s2 = 0.0;
    int r0 = chunk * 128;
    for (int r = r0; r < r0 + 128; ++r) {
        double v = h[(size_t)r * N_DIM + m];
        s += v;
        s2 = fma(v, v, s2);
    }
    psum[chunk * N_DIM + m] = s;
    psum2[chunk * N_DIM + m] = s2;
}

__global__ __launch_bounds__(256)
void col_stats_final(const double* __restrict__ psum, const double* __restrict__ psum2,
                     const float* __restrict__ gamma, const float* __restrict__ beta,
                     double* __restrict__ scale, double* __restrict__ shift) {
    int m = blockIdx.x * 256 + threadIdx.x;
    double s = 0.0, s2 = 0.0;
    for (int c = 0; c < 16; ++c) { s += psum[c * N_DIM + m]; s2 += psum2[c * N_DIM + m]; }
    double mean = s * (1.0 / 2048.0);
    double var = s2 * (1.0 / 2048.0) - mean * mean;
    double istd = 1.0 / sqrt(var + 1e-5);
    double sc = istd * (double)gamma[m];
    scale[m] = sc;
    shift[m] = (double)beta[m] - mean * sc;
}

// ---- fused BN-apply + triple LIF + output ---------------------------------
__global__ __launch_bounds__(256)
void fused_lif_kernel(const float* __restrict__ x, const double* __restrict__ h,
                      const double* __restrict__ scale, const double* __restrict__ shift,
                      const double* __restrict__ ssum, const double* __restrict__ tsum,
                      float* __restrict__ out) {
    int idx = blockIdx.x * 256 + threadIdx.x;     // b*N + n
    int n = idx & (N_DIM - 1);
    int b = idx >> 11;
    double sc = scale[n], sh = shift[n];
    double ts = tsum[idx];
    double v1 = 0.0, v2 = 0.0, v3 = 0.0;
    for (int t = 0; t < T_DIM; ++t) {
        size_t off = (size_t)(t * B_DIM + b) * N_DIM + n;
        double hv = fma(h[off], sc, sh);
        v1 = v1 * 0.5 + hv;
        bool s1 = (v1 >= 1.0); if (s1) v1 = 0.0;
        double in2 = s1 ? ssum[t * B_DIM + b] : 0.0;
        v2 = v2 * 0.5 + in2;
        bool s2 = (v2 >= 1.0); if (s2) v2 = 0.0;
        double in3 = s1 ? ts : 0.0;
        v3 = v3 * 0.5 + in3;
        bool s3 = (v3 >= 1.0); if (s3) v3 = 0.0;
        out[off] = x[off] + ((s2 && s3) ? 1.0f : 0.0f);
    }
}

extern "C" void kernel_launch(void* const* d_in, const int* in_sizes, int n_in,
                              void* d_out, int out_size, void* d_ws, size_t ws_size,
                              hipStream_t stream) {
    const float* x     = (const float*)d_in[0];   // [16,128,2048]
    const float* W     = (const float*)d_in[1];   // [2048,2048]
    const float* gamma = (const float*)d_in[2];   // [2048]
    const float* beta  = (const float*)d_in[3];   // [2048]
    float* out = (float*)d_out;

    char* ws = (char*)d_ws;
    double* h     = (double*)(ws + WS_H);
    double* ssum  = (double*)(ws + WS_SSUM);
    double* tsum  = (double*)(ws + WS_TSUM);
    double* psum  = (double*)(ws + WS_PSUM);
    double* psum2 = (double*)(ws + WS_PSUM2);
    double* scale = (double*)(ws + WS_SCALE);
    double* shift = (double*)(ws + WS_SHIFT);

    spatial_sum_kernel<<<TB, 256, 0, stream>>>(x, ssum);
    temporal_sum_kernel<<<(B_DIM * N_DIM) / 256, 256, 0, stream>>>(x, tsum);
    gemm_f64_v2<<<dim3(N_DIM / 64, TB / 64), 64, 0, stream>>>(x, W, h);
    col_stats_partial<<<dim3(8, 16), 256, 0, stream>>>(h, psum, psum2);
    col_stats_final<<<8, 256, 0, stream>>>(psum, psum2, gamma, beta, scale, shift);
    fused_lif_kernel<<<(B_DIM * N_DIM) / 256, 256, 0, stream>>>(x, h, scale, shift, ssum, tsum, out);
}

// Round 4
// 466.944 us; speedup vs baseline: 1.3580x; 1.0210x over previous
//
#include <hip/hip_runtime.h>
#include <math.h>

// Problem constants
#define T_DIM 16
#define B_DIM 128
#define N_DIM 2048
#define TB    (T_DIM * B_DIM)   // 2048 rows of the GEMM

// Workspace layout (bytes). Total ~36.3 MB.
#define WS_H      0
#define WS_SSUM   33554432
#define WS_TSUM   33570816
#define WS_PSUM   35667968
#define WS_PSUM2  35930112
#define WS_SCALE  36192256
#define WS_SHIFT  36208640

typedef __attribute__((ext_vector_type(2))) double d2;

// ---- spatial sum over last dim: one block per (t,b) row -------------------
__global__ __launch_bounds__(256)
void spatial_sum_kernel(const float* __restrict__ x, double* __restrict__ ssum) {
    int row = blockIdx.x;           // 0..TB-1  (= t*B + b)
    int tid = threadIdx.x;
    const float* xr = x + (size_t)row * N_DIM;
    double s = 0.0;
    for (int i = tid; i < N_DIM; i += 256) s += (double)xr[i];
    for (int off = 32; off > 0; off >>= 1) s += __shfl_down(s, off, 64);
    __shared__ double wsum[4];
    int lane = tid & 63, wv = tid >> 6;
    if (lane == 0) wsum[wv] = s;
    __syncthreads();
    if (tid == 0) ssum[row] = (wsum[0] + wsum[1]) + (wsum[2] + wsum[3]);
}

// ---- temporal sum over t: one thread per (b,n) ----------------------------
__global__ __launch_bounds__(256)
void temporal_sum_kernel(const float* __restrict__ x, double* __restrict__ tsum) {
    int idx = blockIdx.x * 256 + threadIdx.x;     // b*N + n
    double s = 0.0;
    for (int t = 0; t < T_DIM; ++t)
        s += (double)x[(size_t)t * (B_DIM * N_DIM) + idx];
    tsum[idx] = s;
}

// ---- GEMM h[row,m] = sum_n x[row,n] * W[m,n], fp64 vector FMA -------------
// v3: 64x64 tile, ONE wave per block, 8x8 doubles/thread.
// LDS staged as FP32 in [k][row] layout (stride 68 floats): per k-step only
// 4x ds_read_b128 (16 floats) + 16 exact cvt_f64_f32 + 64 v_fma_f64.
// Per-thread rows/cols are contiguous 4-groups: {4ty..4ty+3, 32+4ty..+3}.
// Reads are 8-lane broadcasts over banks 4g..4g+3 (g=0..7) -> conflict-free.
// Per-element accumulation: k ascending, f64 fma on f64(f32) values ->
// h bit-identical to R1/R3 (absmax 0.0).
#define BK 16
#define LDSS 68   // floats; k*68*4B = 272B (16B-aligned), +4ty/+32 aligned
__global__ __launch_bounds__(64, 1)
void gemm_f64_v3(const float* __restrict__ A, const float* __restrict__ Bw,
                 double* __restrict__ C) {
    __shared__ __align__(16) float As[BK * LDSS];
    __shared__ __align__(16) float Bs[BK * LDSS];
    const int t  = threadIdx.x;     // 0..63
    const int tx = t & 7;           // col 4-group
    const int ty = t >> 3;          // row 4-group
    const int row0 = blockIdx.y * 64;
    const int col0 = blockIdx.x * 64;

    const float* Ag = A  + (size_t)(row0 + t) * N_DIM;  // thread stages row t
    const float* Bg = Bw + (size_t)(col0 + t) * N_DIM;

    double acc[8][8];
#pragma unroll
    for (int i = 0; i < 8; ++i)
#pragma unroll
        for (int j = 0; j < 8; ++j) acc[i][j] = 0.0;

    // prefetch tile 0
    float4 sa[4], sb[4];
#pragma unroll
    for (int j = 0; j < 4; ++j) {
        sa[j] = *(const float4*)(Ag + 4 * j);
        sb[j] = *(const float4*)(Bg + 4 * j);
    }

    for (int k0 = 0; k0 < N_DIM; k0 += BK) {
        __syncthreads();
#pragma unroll
        for (int j = 0; j < 4; ++j) {
            As[(4 * j + 0) * LDSS + t] = sa[j].x;
            As[(4 * j + 1) * LDSS + t] = sa[j].y;
            As[(4 * j + 2) * LDSS + t] = sa[j].z;
            As[(4 * j + 3) * LDSS + t] = sa[j].w;
            Bs[(4 * j + 0) * LDSS + t] = sb[j].x;
            Bs[(4 * j + 1) * LDSS + t] = sb[j].y;
            Bs[(4 * j + 2) * LDSS + t] = sb[j].z;
            Bs[(4 * j + 3) * LDSS + t] = sb[j].w;
        }
        __syncthreads();
        if (k0 + BK < N_DIM) {          // prefetch next tile (overlaps compute)
#pragma unroll
            for (int j = 0; j < 4; ++j) {
                sa[j] = *(const float4*)(Ag + k0 + BK + 4 * j);
                sb[j] = *(const float4*)(Bg + k0 + BK + 4 * j);
            }
        }
#pragma unroll
        for (int k = 0; k < BK; ++k) {
            float4 alo = *(const float4*)&As[k * LDSS + 4 * ty];
            float4 ahi = *(const float4*)&As[k * LDSS + 32 + 4 * ty];
            float4 blo = *(const float4*)&Bs[k * LDSS + 4 * tx];
            float4 bhi = *(const float4*)&Bs[k * LDSS + 32 + 4 * tx];
            double a[8], b[8];
            a[0] = (double)alo.x; a[1] = (double)alo.y;
            a[2] = (double)alo.z; a[3] = (double)alo.w;
            a[4] = (double)ahi.x; a[5] = (double)ahi.y;
            a[6] = (double)ahi.z; a[7] = (double)ahi.w;
            b[0] = (double)blo.x; b[1] = (double)blo.y;
            b[2] = (double)blo.z; b[3] = (double)blo.w;
            b[4] = (double)bhi.x; b[5] = (double)bhi.y;
            b[6] = (double)bhi.z; b[7] = (double)bhi.w;
#pragma unroll
            for (int i = 0; i < 8; ++i)
#pragma unroll
                for (int j = 0; j < 8; ++j)
                    acc[i][j] = fma(a[i], b[j], acc[i][j]);
        }
    }

    // write-out: rows {4ty+i, 32+4ty+i}, cols {4tx+j, 32+4tx+j}
#pragma unroll
    for (int i = 0; i < 8; ++i) {
        int r = row0 + ((i < 4) ? (4 * ty + i) : (32 + 4 * ty + i - 4));
        double* Crow = C + (size_t)r * N_DIM + col0;
#pragma unroll
        for (int jg = 0; jg < 2; ++jg) {
            int cbase = (jg == 0) ? (4 * tx) : (32 + 4 * tx);
            d2 v0, v1;
            v0.x = acc[i][4 * jg + 0]; v0.y = acc[i][4 * jg + 1];
            v1.x = acc[i][4 * jg + 2]; v1.y = acc[i][4 * jg + 3];
            *(d2*)(Crow + cbase)     = v0;
            *(d2*)(Crow + cbase + 2) = v1;
        }
    }
}

// ---- BN column stats, two-stage deterministic -----------------------------
__global__ __launch_bounds__(256)
void col_stats_partial(const double* __restrict__ h, double* __restrict__ psum,
                       double* __restrict__ psum2) {
    int m = blockIdx.x * 256 + threadIdx.x;       // 8 col blocks
    int chunk = blockIdx.y;                        // 16 row chunks of 128
    double s = 0.0, s2 = 0.0;
    int r0 = chunk * 128;
    for (int r = r0; r < r0 + 128; ++r) {
        double v = h[(size_t)r * N_DIM + m];
        s += v;
        s2 = fma(v, v, s2);
    }
    psum[chunk * N_DIM + m] = s;
    psum2[chunk * N_DIM + m] = s2;
}

__global__ __launch_bounds__(256)
void col_stats_final(const double* __restrict__ psum, const double* __restrict__ psum2,
                     const float* __restrict__ gamma, const float* __restrict__ beta,
                     double* __restrict__ scale, double* __restrict__ shift) {
    int m = blockIdx.x * 256 + threadIdx.x;
    double s = 0.0, s2 = 0.0;
    for (int c = 0; c < 16; ++c) { s += psum[c * N_DIM + m]; s2 += psum2[c * N_DIM + m]; }
    double mean = s * (1.0 / 2048.0);
    double var = s2 * (1.0 / 2048.0) - mean * mean;
    double istd = 1.0 / sqrt(var + 1e-5);
    double sc = istd * (double)gamma[m];
    scale[m] = sc;
    shift[m] = (double)beta[m] - mean * sc;
}

// ---- fused BN-apply + triple LIF + output ---------------------------------
__global__ __launch_bounds__(256)
void fused_lif_kernel(const float* __restrict__ x, const double* __restrict__ h,
                      const double* __restrict__ scale, const double* __restrict__ shift,
                      const double* __restrict__ ssum, const double* __restrict__ tsum,
                      float* __restrict__ out) {
    int idx = blockIdx.x * 256 + threadIdx.x;     // b*N + n
    int n = idx & (N_DIM - 1);
    int b = idx >> 11;
    double sc = scale[n], sh = shift[n];
    double ts = tsum[idx];
    double v1 = 0.0, v2 = 0.0, v3 = 0.0;
    for (int t = 0; t < T_DIM; ++t) {
        size_t off = (size_t)(t * B_DIM + b) * N_DIM + n;
        double hv = fma(h[off], sc, sh);
        v1 = v1 * 0.5 + hv;
        bool s1 = (v1 >= 1.0); if (s1) v1 = 0.0;
        double in2 = s1 ? ssum[t * B_DIM + b] : 0.0;
        v2 = v2 * 0.5 + in2;
        bool s2 = (v2 >= 1.0); if (s2) v2 = 0.0;
        double in3 = s1 ? ts : 0.0;
        v3 = v3 * 0.5 + in3;
        bool s3 = (v3 >= 1.0); if (s3) v3 = 0.0;
        out[off] = x[off] + ((s2 && s3) ? 1.0f : 0.0f);
    }
}

extern "C" void kernel_launch(void* const* d_in, const int* in_sizes, int n_in,
                              void* d_out, int out_size, void* d_ws, size_t ws_size,
                              hipStream_t stream) {
    const float* x     = (const float*)d_in[0];   // [16,128,2048]
    const float* W     = (const float*)d_in[1];   // [2048,2048]
    const float* gamma = (const float*)d_in[2];   // [2048]
    const float* beta  = (const float*)d_in[3];   // [2048]
    float* out = (float*)d_out;

    char* ws = (char*)d_ws;
    double* h     = (double*)(ws + WS_H);
    double* ssum  = (double*)(ws + WS_SSUM);
    double* tsum  = (double*)(ws + WS_TSUM);
    double* psum  = (double*)(ws + WS_PSUM);
    double* psum2 = (double*)(ws + WS_PSUM2);
    double* scale = (double*)(ws + WS_SCALE);
    double* shift = (double*)(ws + WS_SHIFT);

    spatial_sum_kernel<<<TB, 256, 0, stream>>>(x, ssum);
    temporal_sum_kernel<<<(B_DIM * N_DIM) / 256, 256, 0, stream>>>(x, tsum);
    gemm_f64_v3<<<dim3(N_DIM / 64, TB / 64), 64, 0, stream>>>(x, W, h);
    col_stats_partial<<<dim3(8, 16), 256, 0, stream>>>(h, psum, psum2);
    col_stats_final<<<8, 256, 0, stream>>>(psum, psum2, gamma, beta, scale, shift);
    fused_lif_kernel<<<(B_DIM * N_DIM) / 256, 256, 0, stream>>>(x, h, scale, shift, ssum, tsum, out);
}

// Round 5
// 442.798 us; speedup vs baseline: 1.4321x; 1.0545x over previous
//
#include <hip/hip_runtime.h>
#include <math.h>

// Problem constants
#define T_DIM 16
#define B_DIM 128
#define N_DIM 2048
#define TB    (T_DIM * B_DIM)   // 2048 rows of the GEMM

// Workspace layout (bytes). Total ~36.3 MB.
#define WS_H      0
#define WS_SSUM   33554432
#define WS_TSUM   33570816
#define WS_PSUM   35667968
#define WS_PSUM2  35930112
#define WS_SCALE  36192256
#define WS_SHIFT  36208640

typedef __attribute__((ext_vector_type(2))) double d2;

// ---- spatial sum over last dim: one block per (t,b) row -------------------
__global__ __launch_bounds__(256)
void spatial_sum_kernel(const float* __restrict__ x, double* __restrict__ ssum) {
    int row = blockIdx.x;           // 0..TB-1  (= t*B + b)
    int tid = threadIdx.x;
    const float* xr = x + (size_t)row * N_DIM;
    double s = 0.0;
    for (int i = tid; i < N_DIM; i += 256) s += (double)xr[i];
    for (int off = 32; off > 0; off >>= 1) s += __shfl_down(s, off, 64);
    __shared__ double wsum[4];
    int lane = tid & 63, wv = tid >> 6;
    if (lane == 0) wsum[wv] = s;
    __syncthreads();
    if (tid == 0) ssum[row] = (wsum[0] + wsum[1]) + (wsum[2] + wsum[3]);
}

// ---- temporal sum over t: one thread per (b,n) ----------------------------
__global__ __launch_bounds__(256)
void temporal_sum_kernel(const float* __restrict__ x, double* __restrict__ tsum) {
    int idx = blockIdx.x * 256 + threadIdx.x;     // b*N + n
    double s = 0.0;
    for (int t = 0; t < T_DIM; ++t)
        s += (double)x[(size_t)t * (B_DIM * N_DIM) + idx];
    tsum[idx] = s;
}

// ---- GEMM h[row,m] = sum_n x[row,n] * W[m,n], fp64 vector FMA -------------
// v4: 64x64 tile, TWO waves per block, in-block split-K.
// Wave w owns k-tiles k0 = w*16, w*16+32, ... with PRIVATE LDS staging
// buffers -> the main loop has NO __syncthreads (same-wave DS ordering is
// HW-guaranteed); 2 waves/SIMD cover each other's LDS/global latency.
// Per k-step/lane: 4x ds_read_b128 (f32) + 16 exact cvt + 64 v_fma_f64.
// Epilogue: wave1 dumps acc to LDS (32KB, reuses staging), wave0 adds and
// stores. fp64 k-order change vs np ref ~1e-13 -- far below spike margins.
#define BK 16
#define LDSS 68   // floats; k*68*4B rows, 16B-aligned fragment reads
__global__ __launch_bounds__(128, 2)
void gemm_f64_v4(const float* __restrict__ A, const float* __restrict__ Bw,
                 double* __restrict__ C) {
    __shared__ __align__(16) char smem[32768];    // staging (17KB) / combine (32KB)
    const int t    = threadIdx.x;
    const int lane = t & 63;
    const int w    = t >> 6;                      // wave id 0/1
    const int tx   = lane & 7;                    // col 4-group
    const int ty   = lane >> 3;                   // row 4-group
    const int row0 = blockIdx.y * 64;
    const int col0 = blockIdx.x * 64;

    float* Asw = (float*)smem + (size_t)w * 2176; // 1088 floats A + 1088 B per wave
    float* Bsw = Asw + 1088;

    const float* Ag = A  + (size_t)(row0 + lane) * N_DIM;  // lane stages row `lane`
    const float* Bg = Bw + (size_t)(col0 + lane) * N_DIM;

    double acc[8][8];
#pragma unroll
    for (int i = 0; i < 8; ++i)
#pragma unroll
        for (int j = 0; j < 8; ++j) acc[i][j] = 0.0;

    const int kw = w * BK;                        // this wave's first k-tile
    // prefetch tile 0 of this wave
    float4 sa[4], sb[4];
#pragma unroll
    for (int j = 0; j < 4; ++j) {
        sa[j] = *(const float4*)(Ag + kw + 4 * j);
        sb[j] = *(const float4*)(Bg + kw + 4 * j);
    }

    for (int k0 = kw; k0 < N_DIM; k0 += 2 * BK) {
        // stage into private buffers (no barrier: private per wave,
        // same-wave DS ops are processed in order)
#pragma unroll
        for (int j = 0; j < 4; ++j) {
            Asw[(4 * j + 0) * LDSS + lane] = sa[j].x;
            Asw[(4 * j + 1) * LDSS + lane] = sa[j].y;
            Asw[(4 * j + 2) * LDSS + lane] = sa[j].z;
            Asw[(4 * j + 3) * LDSS + lane] = sa[j].w;
            Bsw[(4 * j + 0) * LDSS + lane] = sb[j].x;
            Bsw[(4 * j + 1) * LDSS + lane] = sb[j].y;
            Bsw[(4 * j + 2) * LDSS + lane] = sb[j].z;
            Bsw[(4 * j + 3) * LDSS + lane] = sb[j].w;
        }
        if (k0 + 2 * BK < N_DIM) {   // prefetch this wave's next tile
#pragma unroll
            for (int j = 0; j < 4; ++j) {
                sa[j] = *(const float4*)(Ag + k0 + 2 * BK + 4 * j);
                sb[j] = *(const float4*)(Bg + k0 + 2 * BK + 4 * j);
            }
        }
#pragma unroll
        for (int k = 0; k < BK; ++k) {
            float4 alo = *(const float4*)&Asw[k * LDSS + 4 * ty];
            float4 ahi = *(const float4*)&Asw[k * LDSS + 32 + 4 * ty];
            float4 blo = *(const float4*)&Bsw[k * LDSS + 4 * tx];
            float4 bhi = *(const float4*)&Bsw[k * LDSS + 32 + 4 * tx];
            double a[8], b[8];
            a[0] = (double)alo.x; a[1] = (double)alo.y;
            a[2] = (double)alo.z; a[3] = (double)alo.w;
            a[4] = (double)ahi.x; a[5] = (double)ahi.y;
            a[6] = (double)ahi.z; a[7] = (double)ahi.w;
            b[0] = (double)blo.x; b[1] = (double)blo.y;
            b[2] = (double)blo.z; b[3] = (double)blo.w;
            b[4] = (double)bhi.x; b[5] = (double)bhi.y;
            b[6] = (double)bhi.z; b[7] = (double)bhi.w;
#pragma unroll
            for (int i = 0; i < 8; ++i)
#pragma unroll
                for (int j = 0; j < 8; ++j)
                    acc[i][j] = fma(a[i], b[j], acc[i][j]);
        }
    }

    // ---- cross-wave combine + store (wave1 -> LDS, wave0 adds) ----
    __syncthreads();                 // wave0 done reading its staging region
    double* cbuf = (double*)smem;    // 4096 doubles = 32KB
    if (w == 1) {
#pragma unroll
        for (int e = 0; e < 64; ++e)
            cbuf[e * 64 + lane] = acc[e >> 3][e & 7];
    }
    __syncthreads();
    if (w == 0) {
#pragma unroll
        for (int i = 0; i < 8; ++i) {
            int r = row0 + ((i < 4) ? (4 * ty + i) : (32 + 4 * ty + i - 4));
            double* Crow = C + (size_t)r * N_DIM + col0;
#pragma unroll
            for (int jg = 0; jg < 2; ++jg) {
                int cbase = (jg == 0) ? (4 * tx) : (32 + 4 * tx);
                d2 v0, v1;
                v0.x = acc[i][4 * jg + 0] + cbuf[(i * 8 + 4 * jg + 0) * 64 + lane];
                v0.y = acc[i][4 * jg + 1] + cbuf[(i * 8 + 4 * jg + 1) * 64 + lane];
                v1.x = acc[i][4 * jg + 2] + cbuf[(i * 8 + 4 * jg + 2) * 64 + lane];
                v1.y = acc[i][4 * jg + 3] + cbuf[(i * 8 + 4 * jg + 3) * 64 + lane];
                *(d2*)(Crow + cbase)     = v0;
                *(d2*)(Crow + cbase + 2) = v1;
            }
        }
    }
}

// ---- BN column stats, two-stage deterministic -----------------------------
__global__ __launch_bounds__(256)
void col_stats_partial(const double* __restrict__ h, double* __restrict__ psum,
                       double* __restrict__ psum2) {
    int m = blockIdx.x * 256 + threadIdx.x;       // 8 col blocks
    int chunk = blockIdx.y;                        // 16 row chunks of 128
    double s = 0.0, s2 = 0.0;
    int r0 = chunk * 128;
    for (int r = r0; r < r0 + 128; ++r) {
        double v = h[(size_t)r * N_DIM + m];
        s += v;
        s2 = fma(v, v, s2);
    }
    psum[chunk * N_DIM + m] = s;
    psum2[chunk * N_DIM + m] = s2;
}

__global__ __launch_bounds__(256)
void col_stats_final(const double* __restrict__ psum, const double* __restrict__ psum2,
                     const float* __restrict__ gamma, const float* __restrict__ beta,
                     double* __restrict__ scale, double* __restrict__ shift) {
    int m = blockIdx.x * 256 + threadIdx.x;
    double s = 0.0, s2 = 0.0;
    for (int c = 0; c < 16; ++c) { s += psum[c * N_DIM + m]; s2 += psum2[c * N_DIM + m]; }
    double mean = s * (1.0 / 2048.0);
    double var = s2 * (1.0 / 2048.0) - mean * mean;
    double istd = 1.0 / sqrt(var + 1e-5);
    double sc = istd * (double)gamma[m];
    scale[m] = sc;
    shift[m] = (double)beta[m] - mean * sc;
}

// ---- fused BN-apply + triple LIF + output ---------------------------------
__global__ __launch_bounds__(256)
void fused_lif_kernel(const float* __restrict__ x, const double* __restrict__ h,
                      const double* __restrict__ scale, const double* __restrict__ shift,
                      const double* __restrict__ ssum, const double* __restrict__ tsum,
                      float* __restrict__ out) {
    int idx = blockIdx.x * 256 + threadIdx.x;     // b*N + n
    int n = idx & (N_DIM - 1);
    int b = idx >> 11;
    double sc = scale[n], sh = shift[n];
    double ts = tsum[idx];
    double v1 = 0.0, v2 = 0.0, v3 = 0.0;
    for (int t = 0; t < T_DIM; ++t) {
        size_t off = (size_t)(t * B_DIM + b) * N_DIM + n;
        double hv = fma(h[off], sc, sh);
        v1 = v1 * 0.5 + hv;
        bool s1 = (v1 >= 1.0); if (s1) v1 = 0.0;
        double in2 = s1 ? ssum[t * B_DIM + b] : 0.0;
        v2 = v2 * 0.5 + in2;
        bool s2 = (v2 >= 1.0); if (s2) v2 = 0.0;
        double in3 = s1 ? ts : 0.0;
        v3 = v3 * 0.5 + in3;
        bool s3 = (v3 >= 1.0); if (s3) v3 = 0.0;
        out[off] = x[off] + ((s2 && s3) ? 1.0f : 0.0f);
    }
}

extern "C" void kernel_launch(void* const* d_in, const int* in_sizes, int n_in,
                              void* d_out, int out_size, void* d_ws, size_t ws_size,
                              hipStream_t stream) {
    const float* x     = (const float*)d_in[0];   // [16,128,2048]
    const float* W     = (const float*)d_in[1];   // [2048,2048]
    const float* gamma = (const float*)d_in[2];   // [2048]
    const float* beta  = (const float*)d_in[3];   // [2048]
    float* out = (float*)d_out;

    char* ws = (char*)d_ws;
    double* h     = (double*)(ws + WS_H);
    double* ssum  = (double*)(ws + WS_SSUM);
    double* tsum  = (double*)(ws + WS_TSUM);
    double* psum  = (double*)(ws + WS_PSUM);
    double* psum2 = (double*)(ws + WS_PSUM2);
    double* scale = (double*)(ws + WS_SCALE);
    double* shift = (double*)(ws + WS_SHIFT);

    spatial_sum_kernel<<<TB, 256, 0, stream>>>(x, ssum);
    temporal_sum_kernel<<<(B_DIM * N_DIM) / 256, 256, 0, stream>>>(x, tsum);
    gemm_f64_v4<<<dim3(N_DIM / 64, TB / 64), 128, 0, stream>>>(x, W, h);
    col_stats_partial<<<dim3(8, 16), 256, 0, stream>>>(h, psum, psum2);
    col_stats_final<<<8, 256, 0, stream>>>(psum, psum2, gamma, beta, scale, shift);
    fused_lif_kernel<<<(B_DIM * N_DIM) / 256, 256, 0, stream>>>(x, h, scale, shift, ssum, tsum, out);
}

// Round 6
// 438.348 us; speedup vs baseline: 1.4466x; 1.0102x over previous
//
#include <hip/hip_runtime.h>
#include <math.h>

// Problem constants
#define T_DIM 16
#define B_DIM 128
#define N_DIM 2048
#define TB    (T_DIM * B_DIM)   // 2048 rows of the GEMM

// Workspace layout (bytes). Total ~36.75 MB.
//   h     [2048][2048] f64 @ 0
//   tsum  [B*N]        f64 @ 33554432
//   psum  [32][2048]   f64 @ 35651584   (per-rowband col sums)
//   psum2 [32][2048]   f64 @ 36175872   (per-rowband col sq-sums)
//   ssum  [TB]         f64 @ 36700160
//   scale [N]          f64 @ 36716544
//   shift [N]          f64 @ 36732928
#define WS_H      0
#define WS_TSUM   33554432
#define WS_PSUM   35651584
#define WS_PSUM2  36175872
#define WS_SSUM   36700160
#define WS_SCALE  36716544
#define WS_SHIFT  36732928

typedef __attribute__((ext_vector_type(2))) double d2;

// ---- spatial sum over last dim: one block per (t,b) row -------------------
__global__ __launch_bounds__(256)
void spatial_sum_kernel(const float* __restrict__ x, double* __restrict__ ssum) {
    int row = blockIdx.x;           // 0..TB-1  (= t*B + b)
    int tid = threadIdx.x;
    const float* xr = x + (size_t)row * N_DIM;
    double s = 0.0;
    for (int i = tid; i < N_DIM; i += 256) s += (double)xr[i];
    for (int off = 32; off > 0; off >>= 1) s += __shfl_down(s, off, 64);
    __shared__ double wsum[4];
    int lane = tid & 63, wv = tid >> 6;
    if (lane == 0) wsum[wv] = s;
    __syncthreads();
    if (tid == 0) ssum[row] = (wsum[0] + wsum[1]) + (wsum[2] + wsum[3]);
}

// ---- temporal sum over t: one thread per (b,n) ----------------------------
__global__ __launch_bounds__(256)
void temporal_sum_kernel(const float* __restrict__ x, double* __restrict__ tsum) {
    int idx = blockIdx.x * 256 + threadIdx.x;     // b*N + n
    double s = 0.0;
    for (int t = 0; t < T_DIM; ++t)
        s += (double)x[(size_t)t * (B_DIM * N_DIM) + idx];
    tsum[idx] = s;
}

// ---- GEMM h[row,m] = sum_n x[row,n] * W[m,n], fp64 vector FMA -------------
// v5: 64x64 tile, TWO waves per block, in-block split-K, barrier-free
// private LDS staging (same-wave DS ordering is HW-guaranteed).
// NEW vs v4: A staged as F64 (cvt hoisted to staging: 16 cvt/tile instead
// of 128), B staged as F32 (cvt at read). Per k-step/lane: 4x b128 A-read +
// 2x b128 B-read + 8 cvt + 64 v_fma_f64  (292 vs 320 VALU cyc).
// Epilogue additionally computes this block's per-column sum/sumsq over its
// 64 rows (deterministic shuffle tree) -> psum/psum2[rowband][col], killing
// the separate 32MB col_stats_partial pass.
// cvt f32->f64 exact, per-element k-order unchanged -> h bit-identical.
#define BK 16
#define LDSA 66   // doubles per k-row of A stage
#define LDSB 68   // floats  per k-row of B stage
__global__ __launch_bounds__(128, 2)
void gemm_f64_v5(const float* __restrict__ A, const float* __restrict__ Bw,
                 double* __restrict__ C, double* __restrict__ psum,
                 double* __restrict__ psum2) {
    __shared__ __align__(16) char smem[32768];    // staging 25.6KB / combine 32KB
    const int t    = threadIdx.x;
    const int lane = t & 63;
    const int w    = t >> 6;                      // wave id 0/1
    const int tx   = lane & 7;                    // col 4-group
    const int ty   = lane >> 3;                   // row 4-group
    const int row0 = blockIdx.y * 64;
    const int col0 = blockIdx.x * 64;

    // per-wave private staging: A = 16x66 doubles (8448B), B = 16x68 floats (4352B)
    double* Asw = (double*)(smem + (size_t)w * 12800);
    float*  Bsw = (float*)(smem + (size_t)w * 12800 + 8448);

    const float* Ag = A  + (size_t)(row0 + lane) * N_DIM;  // lane stages row `lane`
    const float* Bg = Bw + (size_t)(col0 + lane) * N_DIM;

    double acc[8][8];
#pragma unroll
    for (int i = 0; i < 8; ++i)
#pragma unroll
        for (int j = 0; j < 8; ++j) acc[i][j] = 0.0;

    const int kw = w * BK;                        // this wave's first k-tile
    float4 sa[4], sb[4];
#pragma unroll
    for (int j = 0; j < 4; ++j) {
        sa[j] = *(const float4*)(Ag + kw + 4 * j);
        sb[j] = *(const float4*)(Bg + kw + 4 * j);
    }

    for (int k0 = kw; k0 < N_DIM; k0 += 2 * BK) {
        // stage (private buffers; in-order DS per wave -> no barrier)
#pragma unroll
        for (int j = 0; j < 4; ++j) {
            Asw[(4 * j + 0) * LDSA + lane] = (double)sa[j].x;
            Asw[(4 * j + 1) * LDSA + lane] = (double)sa[j].y;
            Asw[(4 * j + 2) * LDSA + lane] = (double)sa[j].z;
            Asw[(4 * j + 3) * LDSA + lane] = (double)sa[j].w;
            Bsw[(4 * j + 0) * LDSB + lane] = sb[j].x;
            Bsw[(4 * j + 1) * LDSB + lane] = sb[j].y;
            Bsw[(4 * j + 2) * LDSB + lane] = sb[j].z;
            Bsw[(4 * j + 3) * LDSB + lane] = sb[j].w;
        }
        if (k0 + 2 * BK < N_DIM) {   // prefetch this wave's next tile
#pragma unroll
            for (int j = 0; j < 4; ++j) {
                sa[j] = *(const float4*)(Ag + k0 + 2 * BK + 4 * j);
                sb[j] = *(const float4*)(Bg + k0 + 2 * BK + 4 * j);
            }
        }
#pragma unroll
        for (int k = 0; k < BK; ++k) {
            const double* Ak = Asw + k * LDSA;
            d2 a01 = *(const d2*)(Ak + 4 * ty);
            d2 a23 = *(const d2*)(Ak + 4 * ty + 2);
            d2 a45 = *(const d2*)(Ak + 32 + 4 * ty);
            d2 a67 = *(const d2*)(Ak + 32 + 4 * ty + 2);
            float4 blo = *(const float4*)&Bsw[k * LDSB + 4 * tx];
            float4 bhi = *(const float4*)&Bsw[k * LDSB + 32 + 4 * tx];
            double a[8], b[8];
            a[0] = a01.x; a[1] = a01.y; a[2] = a23.x; a[3] = a23.y;
            a[4] = a45.x; a[5] = a45.y; a[6] = a67.x; a[7] = a67.y;
            b[0] = (double)blo.x; b[1] = (double)blo.y;
            b[2] = (double)blo.z; b[3] = (double)blo.w;
            b[4] = (double)bhi.x; b[5] = (double)bhi.y;
            b[6] = (double)bhi.z; b[7] = (double)bhi.w;
#pragma unroll
            for (int i = 0; i < 8; ++i)
#pragma unroll
                for (int j = 0; j < 8; ++j)
                    acc[i][j] = fma(a[i], b[j], acc[i][j]);
        }
    }

    // ---- cross-wave combine: wave1 -> LDS, wave0 adds into acc ----
    __syncthreads();                 // both waves done with staging regions
    double* cbuf = (double*)smem;    // 4096 doubles = 32KB
    if (w == 1) {
#pragma unroll
        for (int e = 0; e < 64; ++e)
            cbuf[e * 64 + lane] = acc[e >> 3][e & 7];
    }
    __syncthreads();
    if (w == 0) {
#pragma unroll
        for (int i = 0; i < 8; ++i)
#pragma unroll
            for (int j = 0; j < 8; ++j)
                acc[i][j] += cbuf[(i * 8 + j) * 64 + lane];

        // store C
#pragma unroll
        for (int i = 0; i < 8; ++i) {
            int r = row0 + ((i < 4) ? (4 * ty + i) : (32 + 4 * ty + i - 4));
            double* Crow = C + (size_t)r * N_DIM + col0;
#pragma unroll
            for (int jg = 0; jg < 2; ++jg) {
                int cbase = (jg == 0) ? (4 * tx) : (32 + 4 * tx);
                d2 v0, v1;
                v0.x = acc[i][4 * jg + 0]; v0.y = acc[i][4 * jg + 1];
                v1.x = acc[i][4 * jg + 2]; v1.y = acc[i][4 * jg + 3];
                *(d2*)(Crow + cbase)     = v0;
                *(d2*)(Crow + cbase + 2) = v1;
            }
        }

        // per-column partial BN stats over this block's 64 rows (deterministic)
        double s[8], q[8];
#pragma unroll
        for (int j = 0; j < 8; ++j) { s[j] = 0.0; q[j] = 0.0; }
#pragma unroll
        for (int i = 0; i < 8; ++i)
#pragma unroll
            for (int j = 0; j < 8; ++j) {
                double v = acc[i][j];
                s[j] += v;
                q[j] = fma(v, v, q[j]);
            }
#pragma unroll
        for (int off = 8; off <= 32; off <<= 1)
#pragma unroll
            for (int j = 0; j < 8; ++j) {
                s[j] += __shfl_xor(s[j], off, 64);
                q[j] += __shfl_xor(q[j], off, 64);
            }
        if (ty == 0) {               // lanes 0..7 hold column totals
            int band = blockIdx.y;
#pragma unroll
            for (int jg = 0; jg < 2; ++jg)
#pragma unroll
                for (int jj = 0; jj < 4; ++jj) {
                    int c = col0 + ((jg == 0) ? (4 * tx + jj) : (32 + 4 * tx + jj));
                    psum [band * N_DIM + c] = s[4 * jg + jj];
                    psum2[band * N_DIM + c] = q[4 * jg + jj];
                }
        }
    }
}

// ---- BN final: reduce 32 rowband partials, build scale/shift --------------
__global__ __launch_bounds__(256)
void col_stats_final(const double* __restrict__ psum, const double* __restrict__ psum2,
                     const float* __restrict__ gamma, const float* __restrict__ beta,
                     double* __restrict__ scale, double* __restrict__ shift) {
    int m = blockIdx.x * 256 + threadIdx.x;
    double s = 0.0, s2 = 0.0;
    for (int c = 0; c < 32; ++c) { s += psum[c * N_DIM + m]; s2 += psum2[c * N_DIM + m]; }
    double mean = s * (1.0 / 2048.0);
    double var = s2 * (1.0 / 2048.0) - mean * mean;
    double istd = 1.0 / sqrt(var + 1e-5);
    double sc = istd * (double)gamma[m];
    scale[m] = sc;
    shift[m] = (double)beta[m] - mean * sc;
}

// ---- fused BN-apply + triple LIF + output ---------------------------------
__global__ __launch_bounds__(256)
void fused_lif_kernel(const float* __restrict__ x, const double* __restrict__ h,
                      const double* __restrict__ scale, const double* __restrict__ shift,
                      const double* __restrict__ ssum, const double* __restrict__ tsum,
                      float* __restrict__ out) {
    int idx = blockIdx.x * 256 + threadIdx.x;     // b*N + n
    int n = idx & (N_DIM - 1);
    int b = idx >> 11;
    double sc = scale[n], sh = shift[n];
    double ts = tsum[idx];
    double v1 = 0.0, v2 = 0.0, v3 = 0.0;
    for (int t = 0; t < T_DIM; ++t) {
        size_t off = (size_t)(t * B_DIM + b) * N_DIM + n;
        double hv = fma(h[off], sc, sh);
        v1 = v1 * 0.5 + hv;
        bool s1 = (v1 >= 1.0); if (s1) v1 = 0.0;
        double in2 = s1 ? ssum[t * B_DIM + b] : 0.0;
        v2 = v2 * 0.5 + in2;
        bool s2 = (v2 >= 1.0); if (s2) v2 = 0.0;
        double in3 = s1 ? ts : 0.0;
        v3 = v3 * 0.5 + in3;
        bool s3 = (v3 >= 1.0); if (s3) v3 = 0.0;
        out[off] = x[off] + ((s2 && s3) ? 1.0f : 0.0f);
    }
}

extern "C" void kernel_launch(void* const* d_in, const int* in_sizes, int n_in,
                              void* d_out, int out_size, void* d_ws, size_t ws_size,
                              hipStream_t stream) {
    const float* x     = (const float*)d_in[0];   // [16,128,2048]
    const float* W     = (const float*)d_in[1];   // [2048,2048]
    const float* gamma = (const float*)d_in[2];   // [2048]
    const float* beta  = (const float*)d_in[3];   // [2048]
    float* out = (float*)d_out;

    char* ws = (char*)d_ws;
    double* h     = (double*)(ws + WS_H);
    double* tsum  = (double*)(ws + WS_TSUM);
    double* psum  = (double*)(ws + WS_PSUM);
    double* psum2 = (double*)(ws + WS_PSUM2);
    double* ssum  = (double*)(ws + WS_SSUM);
    double* scale = (double*)(ws + WS_SCALE);
    double* shift = (double*)(ws + WS_SHIFT);

    spatial_sum_kernel<<<TB, 256, 0, stream>>>(x, ssum);
    temporal_sum_kernel<<<(B_DIM * N_DIM) / 256, 256, 0, stream>>>(x, tsum);
    gemm_f64_v5<<<dim3(N_DIM / 64, TB / 64), 128, 0, stream>>>(x, W, h, psum, psum2);
    col_stats_final<<<8, 256, 0, stream>>>(psum, psum2, gamma, beta, scale, shift);
    fused_lif_kernel<<<(B_DIM * N_DIM) / 256, 256, 0, stream>>>(x, h, scale, shift, ssum, tsum, out);
}